// Round 9
// baseline (1398.364 us; speedup 1.0000x reference)
//
#include <hip/hip_runtime.h>

#define N_FEAT 128
#define HID 256
#define OUT_CH 128

#define NB 256        // CSR-build blocks (per-block histograms)
#define NJ 40         // scan blocks (all co-resident: spin-safe)
#define BLK_N 40      // dst nodes per agg block
#define NBLK 250      // agg blocks (250*40 = 10000 = N)
#define CHUNK 256     // src rows per staged chunk (256*256B = 64KB)
#define NCH 40        // chunks (covers 10240 >= N rows)
#define NKEY (NBLK * NCH)  // 10000 buckets -- fits LDS histogram
#define EBUF 768      // per-chunk edge-list LDS buffer (avg 64, 10-sigma safe)

typedef unsigned short u16;
typedef _Float16 f16x8 __attribute__((ext_vector_type(8)));
typedef float f32x4 __attribute__((ext_vector_type(4)));

// ---------------- f16 pack/unpack helpers ----------------
__device__ __forceinline__ unsigned pack_f16x2(float lo, float hi) {
    union { _Float16 h[2]; unsigned u; } c;
    c.h[0] = (_Float16)lo;
    c.h[1] = (_Float16)hi;
    return c.u;
}
__device__ __forceinline__ float2 unpack_f16x2(unsigned u) {
    union { unsigned u; _Float16 h[2]; } c;
    c.u = u;
    return make_float2((float)c.h[0], (float)c.h[1]);
}
__device__ __forceinline__ u16 f16u(float f) {
    union { _Float16 h; u16 u; } c;
    c.h = (_Float16)f;
    return c.u;
}

// ---------------- CSR build: bucket counting sort ----------------
// Key = (dst/40)*40 + (src>>8) in [0,10000): groups edges by
// (agg-block, src-chunk) so the agg can stream chunks sequentially.
// Second LDS histogram counts per-node degree for dinv.

__global__ __launch_bounds__(256)
void hist_kernel(const int* __restrict__ src, const int* __restrict__ dst,
                 u16* __restrict__ bhk, u16* __restrict__ bhd,
                 int* __restrict__ flag, int E, int N, int chunk) {
    __shared__ int hk[NKEY];
    __shared__ int hd[NKEY];   // per-node degree (N == NKEY == 10000)
    if (blockIdx.x == 0 && threadIdx.x < 64) flag[threadIdx.x] = 0;
    for (int i = threadIdx.x; i < NKEY; i += 256) {
        hk[i] = 0;
        hd[i] = 0;
    }
    __syncthreads();
    int base = blockIdx.x * chunk;
    int lim = min(chunk, E - base);
    for (int i = threadIdx.x; i < lim; i += 256) {
        int d = dst[base + i];
        int s = src[base + i];
        if ((unsigned)d < (unsigned)N && (unsigned)s < (unsigned)N) {
            int key = (d / BLK_N) * NCH + (s >> 8);
            atomicAdd(&hk[key], 1);
            atomicAdd(&hd[d], 1);
        }
    }
    __syncthreads();
    u16* ok = bhk + (size_t)blockIdx.x * NKEY;
    u16* od = bhd + (size_t)blockIdx.x * NKEY;
    for (int i = threadIdx.x; i < NKEY; i += 256) {
        ok[i] = (u16)hk[i];
        od[i] = (u16)hd[i];
    }
}

// Column scan over bucket counts (rewrite bhk to per-block exclusive prefix)
// + global exclusive scan -> kstart; degree column-sum -> dinv.
// 40 blocks co-resident; cross-block prefix via spin flags (proven r4-r7).
__global__ __launch_bounds__(256)
void colscan_scan_kernel(u16* __restrict__ bhk, const u16* __restrict__ bhd,
                         int* __restrict__ kstart, float* __restrict__ dinv,
                         int* __restrict__ flag, int N) {
    int tid = threadIdx.x;
    int b = blockIdx.x;
    int j = b * 256 + tid;
    int run = 0;
    if (j < NKEY) {
        #pragma unroll 8
        for (int bb = 0; bb < NB; bb++) {
            size_t idx = (size_t)bb * NKEY + j;
            int t = bhk[idx];
            bhk[idx] = (u16)run;
            run += t;
        }
        int deg = 0;
        #pragma unroll 8
        for (int bb = 0; bb < NB; bb++) deg += bhd[(size_t)bb * NKEY + j];
        if (j < N) dinv[j] = rsqrtf((float)(deg + 1));
    }
    __shared__ int wsum[4];
    __shared__ int sbase;
    int lane = tid & 63, wv = tid >> 6;
    int incl = run;
    #pragma unroll
    for (int off = 1; off < 64; off <<= 1) {
        int t = __shfl_up(incl, off, 64);
        if (lane >= off) incl += t;
    }
    if (lane == 63) wsum[wv] = incl;
    __syncthreads();
    int wbase = 0;
    #pragma unroll
    for (int k = 0; k < 4; k++)
        if (k < wv) wbase += wsum[k];
    int local_excl = wbase + (incl - run);
    int T_b = wsum[0] + wsum[1] + wsum[2] + wsum[3];
    if (tid == 0)
        __hip_atomic_store(&flag[b], T_b + 1, __ATOMIC_RELAXED,
                           __HIP_MEMORY_SCOPE_AGENT);
    if (tid < 64) {
        int v = 0;
        if (tid < b) {
            int fl;
            do {
                fl = __hip_atomic_load(&flag[tid], __ATOMIC_RELAXED,
                                       __HIP_MEMORY_SCOPE_AGENT);
            } while (fl == 0);
            v = fl - 1;
        }
        #pragma unroll
        for (int off = 1; off < 64; off <<= 1) v += __shfl_xor(v, off, 64);
        if (tid == 0) sbase = v;
    }
    __syncthreads();
    int base = sbase;
    if (j < NKEY) kstart[j] = base + local_excl;
    if (b == NJ - 1 && tid == 0) kstart[NKEY] = base + T_b;
}

// Scatter packed u16 payloads via LDS bucket cursors + fused prescale /
// weight-convert tail (unchanged from r4 structure).
__global__ __launch_bounds__(256)
void scat_kernel(const int* __restrict__ src, const int* __restrict__ dst,
                 const u16* __restrict__ bhk, const int* __restrict__ kstart,
                 u16* __restrict__ csr16,
                 const float* __restrict__ x, const float* __restrict__ dinv,
                 unsigned* __restrict__ xs_b,
                 const float* __restrict__ W1, const float* __restrict__ W2,
                 u16* __restrict__ W1t, u16* __restrict__ W2t,
                 int E, int N, int chunk) {
    __shared__ int cur[NKEY];
    const u16* basep = bhk + (size_t)blockIdx.x * NKEY;
    for (int i = threadIdx.x; i < NKEY; i += 256)
        cur[i] = kstart[i] + (int)basep[i];
    __syncthreads();
    int base = blockIdx.x * chunk;
    int lim = min(chunk, E - base);
    for (int i = threadIdx.x; i < lim; i += 256) {
        int e = base + i;
        int d = dst[e];
        int s = src[e];
        if ((unsigned)d >= (unsigned)N || (unsigned)s >= (unsigned)N) continue;
        int dblk = d / BLK_N;
        int dl = d - dblk * BLK_N;
        int key = dblk * NCH + (s >> 8);
        int pos = atomicAdd(&cur[key], 1);
        if ((unsigned)pos < (unsigned)E)
            csr16[pos] = (u16)((dl << 8) | (s & 255));
    }
    // ---- fused tail: prescale + W1/W2 -> f16 transposed ----
    const int total4 = N * N_FEAT / 4;
    const int stride = NB * 256;
    int g0 = blockIdx.x * 256 + threadIdx.x;
    for (int i = g0; i < total4; i += stride) {
        int row = i >> 5;                // 32 float4 per 128-f row
        float d = dinv[row];
        float4 v = ((const float4*)x)[i];
        uint2 p;
        p.x = pack_f16x2(v.x * d, v.y * d);
        p.y = pack_f16x2(v.z * d, v.w * d);
        ((uint2*)xs_b)[i] = p;
    }
    const int TOTW = N_FEAT * HID + HID * OUT_CH;
    for (int t = g0; t < TOTW; t += stride) {
        if (t < N_FEAT * HID) {          // W1t[n][k] = W1[k][n], f16 [256][128]
            int n = t >> 7, k = t & 127;
            W1t[t] = f16u(W1[(size_t)k * HID + n]);
        } else {                         // W2t[n][k] = W2[k][n], f16 [128][256]
            int j2 = t - N_FEAT * HID;
            int n = j2 >> 8, k = j2 & 255;
            W2t[j2] = f16u(W2[(size_t)k * OUT_CH + n]);
        }
    }
}

// ---------------- Chunked-LDS aggregation (87KB LDS: de-risked r8) --------
// Random 256B gathers are per-CU miss-tracking bound (~13 cyc/line; r3/r5/r7
// falsified wave-MLP/VALU/L1 theories). Convert to sequential streams: each
// block owns 40 dst nodes (f32 acc in LDS) and streams the feature table
// chunk-by-chunk. SINGLE 64KB LDS buffer; pipeline lives in registers
// (r[16] holds chunk c+1 while chunk c is processed; loads for c+2 issue
// right after the buffer write, overlapping processing of c+1).
template <bool EPILOGUE, bool F16OUT>
__global__ __launch_bounds__(256)
void agg_chunked(const unsigned* __restrict__ featb,   // [10240][64] dwords
                 const float* __restrict__ dinv,
                 const int* __restrict__ kstart,        // [NKEY+1]
                 const u16* __restrict__ csr16,
                 const float* __restrict__ bias,
                 void* __restrict__ out) {
    __shared__ float accs[BLK_N * 128];          // 20 KB: [nb][f]=x, [nb][64+f]=y
    __shared__ unsigned buf[CHUNK * 64];         // 64 KB single chunk buffer
    __shared__ u16 ebuf[2][EBUF];                // 3 KB edge-list double buffer
    const int tid = threadIdx.x;
    const int b = blockIdx.x;
    const int wv = tid >> 6;
    const int f = tid & 63;
    const int kb = b * NCH;

    // self-term init: acc = featb[own nodes]
    for (int i = tid; i < BLK_N * 64; i += 256) {
        int nb = i >> 6, ff = i & 63;
        float2 u = unpack_f16x2(featb[(unsigned)(b * BLK_N + nb) * 64 + ff]);
        accs[nb * 128 + ff] = u.x;
        accs[nb * 128 + 64 + ff] = u.y;
    }

    uint4 r[16];
    // prologue: load chunk 0 -> write buf; stage chunk-0 edges; load chunk 1
    #pragma unroll
    for (int k = 0; k < 16; k++) r[k] = ((const uint4*)featb)[k * 256 + tid];
    {
        int e0 = kstart[kb], e1 = kstart[kb + 1];
        int m = min(e1 - e0, EBUF);
        for (int i = tid; i < m; i += 256) ebuf[0][i] = csr16[e0 + i];
    }
    #pragma unroll
    for (int k = 0; k < 16; k++) ((uint4*)buf)[k * 256 + tid] = r[k];  // vmcnt wait
    #pragma unroll
    for (int k = 0; k < 16; k++)
        r[k] = ((const uint4*)featb)[4096 + k * 256 + tid];
    __syncthreads();

    for (int c = 0; c < NCH; c++) {
        // process chunk c from LDS (one edge per wave per step)
        const u16* eb = ebuf[c & 1];
        int e0 = kstart[kb + c];
        int m = kstart[kb + c + 1] - e0;
        for (int i = wv; i < m; i += 4) {
            unsigned p = (i < EBUF) ? (unsigned)eb[i] : (unsigned)csr16[e0 + i];
            int sl = p & 255;
            int dl = p >> 8;
            float2 u = unpack_f16x2(buf[sl * 64 + f]);
            atomicAdd(&accs[dl * 128 + f], u.x);
            atomicAdd(&accs[dl * 128 + 64 + f], u.y);
        }
        __syncthreads();                          // all done reading buf
        if (c + 1 < NCH) {
            #pragma unroll
            for (int k = 0; k < 16; k++)
                ((uint4*)buf)[k * 256 + tid] = r[k];          // chunk c+1
            if (c + 2 < NCH) {
                #pragma unroll
                for (int k = 0; k < 16; k++)
                    r[k] = ((const uint4*)featb)[(size_t)(c + 2) * 4096 + k * 256 + tid];
            }
            int ne0 = kstart[kb + c + 1];
            int nm = min(kstart[kb + c + 2] - ne0, EBUF);
            for (int i = tid; i < nm; i += 256)
                ebuf[(c + 1) & 1][i] = csr16[ne0 + i];
            __syncthreads();
        }
    }

    // epilogue: dinv scale (+bias+relu) and store
    for (int i = tid; i < BLK_N * 64; i += 256) {
        int nb = i >> 6, ff = i & 63;
        int n = b * BLK_N + nb;
        float d = dinv[n];
        float ax = accs[nb * 128 + ff] * d;
        float ay = accs[nb * 128 + 64 + ff] * d;
        if (EPILOGUE) {
            float2 bb = ((const float2*)bias)[ff];
            ax = fmaxf(ax + bb.x, 0.0f);
            ay = fmaxf(ay + bb.y, 0.0f);
        }
        if (F16OUT) {
            ((unsigned*)out)[(unsigned)n * 64 + ff] = pack_f16x2(ax, ay);
        } else {
            float2 rr;
            rr.x = ax;
            rr.y = ay;
            ((float2*)out)[(unsigned)n * 64 + ff] = rr;
        }
    }
}

// ---------------- Fused MLP: t16 = dinv ⊙ (relu(A@W1+b1) @ W2) -------------
// (unchanged, proven r4) MFMA f16 16x16x32, fp32 accum; H stays in LDS.
__global__ __launch_bounds__(256)
void mlp_kernel(const u16* __restrict__ A,     // [>=Mpad][128] f16
                const u16* __restrict__ W1t,   // [256][128] f16
                const u16* __restrict__ W2t,   // [128][256] f16
                const float* __restrict__ b1,
                const float* __restrict__ rscale,
                u16* __restrict__ C,           // [M][128] f16
                int M) {
    __shared__ __align__(16) u16 As[64 * 128];
    __shared__ __align__(16) u16 Wl[256 * 128];
    __shared__ __align__(16) u16 Hl[64 * 256];
    int tid = threadIdx.x;
    int w = tid >> 6;
    int l = tid & 63;
    int m0 = blockIdx.x * 64;
    int g = l >> 4;            // k-group 0..3
    int cl = l & 15;           // frag col/row lane index

    for (int q = tid; q < 1024; q += 256) {
        int r = q >> 4, c = q & 15;
        *(f16x8*)&As[r * 128 + ((c ^ (r & 15)) * 8)] =
            *(const f16x8*)(A + (size_t)(m0 + r) * 128 + c * 8);
    }
    for (int q = tid; q < 4096; q += 256) {
        int r = q >> 4, c = q & 15;
        *(f16x8*)&Wl[r * 128 + ((c ^ (r & 15)) * 8)] =
            *(const f16x8*)(W1t + (size_t)r * 128 + c * 8);
    }
    __syncthreads();

    // phase 1: H[64][256] = relu(A @ W1 + b1)
    {
        f32x4 acc[16];
        const f32x4 zero = {0.f, 0.f, 0.f, 0.f};
        #pragma unroll
        for (int nf = 0; nf < 16; nf++) acc[nf] = zero;
        int rowA = w * 16 + cl;
        #pragma unroll
        for (int kc = 0; kc < 4; kc++) {
            int ch = kc * 4 + g;
            f16x8 af = *(const f16x8*)&As[rowA * 128 + ((ch ^ (rowA & 15)) * 8)];
            #pragma unroll
            for (int nf = 0; nf < 16; nf++) {
                int rb = nf * 16 + cl;
                f16x8 bf = *(const f16x8*)&Wl[rb * 128 + ((ch ^ (rb & 15)) * 8)];
                acc[nf] = __builtin_amdgcn_mfma_f32_16x16x32_f16(af, bf, acc[nf], 0, 0, 0);
            }
        }
        int r0 = g * 4;
        #pragma unroll
        for (int nf = 0; nf < 16; nf++) {
            int col = nf * 16 + cl;
            float bb = b1[col];
            #pragma unroll
            for (int r = 0; r < 4; r++) {
                int lr = w * 16 + r0 + r;
                float v = fmaxf(acc[nf][r] + bb, 0.0f);
                int cc = col >> 3;
                Hl[lr * 256 + ((cc ^ (lr & 31)) * 8) + (col & 7)] = f16u(v);
            }
        }
    }
    __syncthreads();

    for (int q = tid; q < 4096; q += 256) {
        int r = q >> 5, c = q & 31;
        *(f16x8*)&Wl[r * 256 + ((c ^ (r & 31)) * 8)] =
            *(const f16x8*)(W2t + (size_t)r * 256 + c * 8);
    }
    __syncthreads();

    // phase 2: t = dinv ⊙ (H @ W2)
    {
        f32x4 acc[8];
        const f32x4 zero = {0.f, 0.f, 0.f, 0.f};
        #pragma unroll
        for (int nf = 0; nf < 8; nf++) acc[nf] = zero;
        int rowA = w * 16 + cl;
        #pragma unroll
        for (int kc = 0; kc < 8; kc++) {
            int ch = kc * 4 + g;
            f16x8 af = *(const f16x8*)&Hl[rowA * 256 + ((ch ^ (rowA & 31)) * 8)];
            #pragma unroll
            for (int nf = 0; nf < 8; nf++) {
                int rb = nf * 16 + cl;
                f16x8 bf = *(const f16x8*)&Wl[rb * 256 + ((ch ^ (rb & 31)) * 8)];
                acc[nf] = __builtin_amdgcn_mfma_f32_16x16x32_f16(af, bf, acc[nf], 0, 0, 0);
            }
        }
        int r0 = g * 4;
        #pragma unroll
        for (int r = 0; r < 4; r++) {
            int m = m0 + w * 16 + r0 + r;
            if (m >= M) continue;
            float rs = rscale[m];
            #pragma unroll
            for (int nf = 0; nf < 8; nf++) {
                int col = nf * 16 + cl;
                C[(size_t)m * 128 + col] = f16u(acc[nf][r] * rs);
            }
        }
    }
}

// ---------------- launch ----------------

static inline size_t align512(size_t x) { return (x + 511) & ~(size_t)511; }

extern "C" void kernel_launch(void* const* d_in, const int* in_sizes, int n_in,
                              void* d_out, int out_size, void* d_ws, size_t ws_size,
                              hipStream_t stream) {
    const float* x = (const float*)d_in[0];
    const int* ei = (const int*)d_in[1];
    const float* W1 = (const float*)d_in[2];
    const float* b1 = (const float*)d_in[3];
    const float* W2 = (const float*)d_in[4];
    const float* b2 = (const float*)d_in[5];
    float* out = (float*)d_out;

    const int N = in_sizes[0] / N_FEAT;      // 10000
    const int E = in_sizes[1] / 2;           // 640000
    const int* src = ei;
    const int* dst = ei + E;

    const int Mpad = ((N + 63) / 64) * 64;   // 10048 (MFMA staging pad)
    const int ROWS = NCH * CHUNK;            // 10240 staged table rows

    // workspace carve-up (~20 MB)
    char* ws = (char*)d_ws;
    size_t off = 0;
    float* dinv = (float*)(ws + off);    off += align512((size_t)N * 4);
    int* flag = (int*)(ws + off);        off += align512((size_t)64 * 4);
    int* kstart = (int*)(ws + off);      off += align512((size_t)(NKEY + 1) * 4);
    u16* csr16 = (u16*)(ws + off);       off += align512((size_t)E * 2);
    unsigned* xs_b = (unsigned*)(ws + off);  off += align512((size_t)ROWS * 64 * 4);
    u16* agg1h = (u16*)(ws + off);       off += align512((size_t)ROWS * N_FEAT * 2);
    u16* t16 = (u16*)(ws + off);         off += align512((size_t)ROWS * OUT_CH * 2);
    u16* W1t = (u16*)(ws + off);         off += align512((size_t)HID * N_FEAT * 2);
    u16* W2t = (u16*)(ws + off);         off += align512((size_t)OUT_CH * HID * 2);
    u16* bhk = (u16*)(ws + off);         off += align512((size_t)NB * NKEY * 2);
    u16* bhd = (u16*)(ws + off);         off += align512((size_t)NB * NKEY * 2);
    (void)ws_size;
    (void)Mpad;
    const int chunk = (E + NB - 1) / NB;

    // 1. CSR build: bucket hist(+degree) -> colscan+scan -> scat(+tails)
    hist_kernel<<<NB, 256, 0, stream>>>(src, dst, bhk, bhd, flag, E, N, chunk);
    colscan_scan_kernel<<<NJ, 256, 0, stream>>>(bhk, bhd, kstart, dinv, flag, N);
    scat_kernel<<<NB, 256, 0, stream>>>(src, dst, bhk, kstart, csr16,
                                        x, dinv, xs_b, W1, W2, W1t, W2t,
                                        E, N, chunk);

    // 2. agg1h = f16(A_norm @ x)   [chunked-LDS SpMM]
    agg_chunked<false, true><<<NBLK, 256, 0, stream>>>(
        xs_b, dinv, kstart, csr16, nullptr, agg1h);

    // 3. t16 = dinv ⊙ (relu(agg1h @ W1 + b1) @ W2)   [fused MFMA MLP]
    mlp_kernel<<<Mpad / 64, 256, 0, stream>>>(agg1h, W1t, W2t, b1, dinv, t16, N);

    // 4. out = relu(A_norm-aggregate of t16 + b2)   [chunked-LDS SpMM]
    agg_chunked<true, false><<<NBLK, 256, 0, stream>>>(
        (const unsigned*)t16, dinv, kstart, csr16, b2, out);
}

// Round 10
// 174.706 us; speedup vs baseline: 8.0041x; 8.0041x over previous
//
#include <hip/hip_runtime.h>

#define N_FEAT 128
#define HID 256
#define OUT_CH 128

#define NB 256        // CSR-build blocks (per-block histograms)
#define NJ 40         // column-scan blocks (all co-resident: spin-safe)
#define MAXN 10240    // LDS histogram capacity (N=10000)

typedef unsigned short u16;
typedef _Float16 f16x8 __attribute__((ext_vector_type(8)));
typedef float f32x4 __attribute__((ext_vector_type(4)));

// ---------------- f16 pack/unpack helpers ----------------
__device__ __forceinline__ unsigned pack_f16x2(float lo, float hi) {
    union { _Float16 h[2]; unsigned u; } c;
    c.h[0] = (_Float16)lo;
    c.h[1] = (_Float16)hi;
    return c.u;
}
__device__ __forceinline__ float2 unpack_f16x2(unsigned u) {
    union { unsigned u; _Float16 h[2]; } c;
    c.u = u;
    return make_float2((float)c.h[0], (float)c.h[1]);
}
__device__ __forceinline__ u16 f16u(float f) {
    union { _Float16 h; u16 u; } c;
    c.h = (_Float16)f;
    return c.u;
}

// ---------------- CSR build: LDS-histogram counting sort ----------------
// Falsified alternatives: coop-kernel fusion (r2: 141us, grid.sync),
// global-atomic count/scat (r6: 46us scat, atomic-latency), bucket sort +
// chunked-LDS agg (r9: 650us/agg, ds_add serialization).

__global__ __launch_bounds__(256)
void hist_kernel(const int* __restrict__ dst, u16* __restrict__ bh,
                 int* __restrict__ flag, int E, int N, int chunk) {
    __shared__ int hist[MAXN];
    if (blockIdx.x == 0 && threadIdx.x < 64) flag[threadIdx.x] = 0;  // scan flags
    for (int i = threadIdx.x; i < N; i += 256) hist[i] = 0;
    __syncthreads();
    int base = blockIdx.x * chunk;
    int lim = min(chunk, E - base);
    for (int i = threadIdx.x; i < lim; i += 256) {
        int d = dst[base + i];
        if (d >= 0 && d < N) atomicAdd(&hist[d], 1);
    }
    __syncthreads();
    u16* out = bh + (size_t)blockIdx.x * N;
    for (int i = threadIdx.x; i < N; i += 256) out[i] = (u16)hist[i];
}

// Fused column scan + global exclusive scan. 40 blocks, all co-resident ->
// cross-block prefix via device-scope atomic flags (value = total+1, 0 =
// unset); lanes poll predecessors in parallel.
__global__ __launch_bounds__(256)
void colscan_scan_kernel(u16* __restrict__ bh, int* __restrict__ row_start,
                         float* __restrict__ dinv, int* __restrict__ flag,
                         int N) {
    int tid = threadIdx.x;
    int b = blockIdx.x;
    int j = b * 256 + tid;
    int run = 0;
    if (j < N) {
        #pragma unroll 8
        for (int bb = 0; bb < NB; bb++) {
            size_t idx = (size_t)bb * N + j;
            int t = bh[idx];
            bh[idx] = (u16)run;
            run += t;
        }
        dinv[j] = rsqrtf((float)(run + 1));
    }
    __shared__ int wsum[4];
    __shared__ int sbase;
    int lane = tid & 63, wv = tid >> 6;
    int incl = run;
    #pragma unroll
    for (int off = 1; off < 64; off <<= 1) {
        int t = __shfl_up(incl, off, 64);
        if (lane >= off) incl += t;
    }
    if (lane == 63) wsum[wv] = incl;
    __syncthreads();
    int wbase = 0;
    #pragma unroll
    for (int k = 0; k < 4; k++)
        if (k < wv) wbase += wsum[k];
    int local_excl = wbase + (incl - run);
    int T_b = wsum[0] + wsum[1] + wsum[2] + wsum[3];
    if (tid == 0)
        __hip_atomic_store(&flag[b], T_b + 1, __ATOMIC_RELAXED,
                           __HIP_MEMORY_SCOPE_AGENT);
    if (tid < 64) {
        int v = 0;
        if (tid < b) {
            int f;
            do {
                f = __hip_atomic_load(&flag[tid], __ATOMIC_RELAXED,
                                      __HIP_MEMORY_SCOPE_AGENT);
            } while (f == 0);
            v = f - 1;
        }
        #pragma unroll
        for (int off = 1; off < 64; off <<= 1) v += __shfl_xor(v, off, 64);
        if (tid == 0) sbase = v;
    }
    __syncthreads();
    int base = sbase;
    if (j < N) row_start[j] = base + local_excl;
    if (b == NJ - 1 && tid == 0) row_start[N] = base + T_b;
}

// Scatter via LDS cursors + fused prescale / weight-convert tail.
__global__ __launch_bounds__(256)
void scat_kernel(const int* __restrict__ src, const int* __restrict__ dst,
                 const u16* __restrict__ bh,
                 const int* __restrict__ row_start,
                 int* __restrict__ csr_src,
                 const float* __restrict__ x, const float* __restrict__ dinv,
                 unsigned* __restrict__ xs_b,
                 const float* __restrict__ W1, const float* __restrict__ W2,
                 u16* __restrict__ W1t, u16* __restrict__ W2t,
                 int E, int N, int chunk) {
    __shared__ int cur[MAXN];
    const u16* basep = bh + (size_t)blockIdx.x * N;
    for (int i = threadIdx.x; i < N; i += 256)
        cur[i] = row_start[i] + (int)basep[i];
    __syncthreads();
    int base = blockIdx.x * chunk;
    int lim = min(chunk, E - base);
    for (int i = threadIdx.x; i < lim; i += 256) {
        int e = base + i;
        int d = dst[e];
        if (d < 0 || d >= N) continue;
        int pos = atomicAdd(&cur[d], 1);
        if ((unsigned)pos < (unsigned)E) csr_src[pos] = src[e];
    }
    // ---- fused tail: prescale + W1/W2 -> f16 transposed (independent) ----
    const int total4 = N * N_FEAT / 4;
    const int stride = NB * 256;
    int g0 = blockIdx.x * 256 + threadIdx.x;
    for (int i = g0; i < total4; i += stride) {
        int row = i >> 5;                // 32 float4 per 128-f row
        float d = dinv[row];
        float4 v = ((const float4*)x)[i];
        uint2 p;
        p.x = pack_f16x2(v.x * d, v.y * d);
        p.y = pack_f16x2(v.z * d, v.w * d);
        ((uint2*)xs_b)[i] = p;
    }
    const int TOTW = N_FEAT * HID + HID * OUT_CH;
    for (int t = g0; t < TOTW; t += stride) {
        if (t < N_FEAT * HID) {          // W1t[n][k] = W1[k][n], f16 [256][128]
            int n = t >> 7, k = t & 127;
            W1t[t] = f16u(W1[(size_t)k * HID + n]);
        } else {                         // W2t[n][k] = W2[k][n], f16 [128][256]
            int j2 = t - N_FEAT * HID;
            int n = j2 >> 8, k = j2 & 255;
            W2t[j2] = f16u(W2[(size_t)k * OUT_CH + n]);
        }
    }
}

// ---------------- Aggregation: 2 nodes per wave, dual batch-8 pipelines ----
// FROZEN at the empirical floor (~4.8 B/cyc/CU random-gather throughput).
// Falsified: wave-MLP (r3), VALU issue (r5), L1 bypass (r7), LDS-chunked
// SpMM (r9: ds_add serialization), batch-32/pair-gather (prior session).
__device__ __forceinline__ void agg_tail(const unsigned* __restrict__ featb,
                                         const int* __restrict__ csr_src,
                                         int e, int e1, int f,
                                         float& accx, float& accy) {
    for (; e + 4 <= e1; e += 4) {
        int s0 = csr_src[e], s1 = csr_src[e + 1];
        int s2 = csr_src[e + 2], s3 = csr_src[e + 3];
        unsigned w0 = featb[(size_t)s0 * 64 + f];
        unsigned w1 = featb[(size_t)s1 * 64 + f];
        unsigned w2 = featb[(size_t)s2 * 64 + f];
        unsigned w3 = featb[(size_t)s3 * 64 + f];
        float2 u0 = unpack_f16x2(w0), u1 = unpack_f16x2(w1);
        float2 u2 = unpack_f16x2(w2), u3 = unpack_f16x2(w3);
        accx += u0.x + u1.x + u2.x + u3.x;
        accy += u0.y + u1.y + u2.y + u3.y;
    }
    for (; e < e1; ++e) {
        float2 u = unpack_f16x2(featb[(size_t)csr_src[e] * 64 + f]);
        accx += u.x;
        accy += u.y;
    }
}

__device__ __forceinline__ void agg_full(const unsigned* __restrict__ featb,
                                         const int* __restrict__ csr_src,
                                         int e, int e1, int f,
                                         float& accx, float& accy) {
    if (e + 8 <= e1) {
        int s_cur[8];
        #pragma unroll
        for (int j = 0; j < 8; j++) s_cur[j] = csr_src[e + j];
        e += 8;
        for (; e + 8 <= e1; e += 8) {
            unsigned w[8];
            #pragma unroll
            for (int j = 0; j < 8; j++) w[j] = featb[(size_t)s_cur[j] * 64 + f];
            int s_nxt[8];
            #pragma unroll
            for (int j = 0; j < 8; j++) s_nxt[j] = csr_src[e + j];
            #pragma unroll
            for (int j = 0; j < 8; j++) {
                float2 u = unpack_f16x2(w[j]);
                accx += u.x;
                accy += u.y;
            }
            #pragma unroll
            for (int j = 0; j < 8; j++) s_cur[j] = s_nxt[j];
        }
        unsigned w[8];
        #pragma unroll
        for (int j = 0; j < 8; j++) w[j] = featb[(size_t)s_cur[j] * 64 + f];
        #pragma unroll
        for (int j = 0; j < 8; j++) {
            float2 u = unpack_f16x2(w[j]);
            accx += u.x;
            accy += u.y;
        }
    }
    agg_tail(featb, csr_src, e, e1, f, accx, accy);
}

template <bool EPILOGUE, bool F16OUT>
__global__ __launch_bounds__(256)
void agg_kernel(const unsigned* __restrict__ featb,
                const float* __restrict__ dinv,
                const int* __restrict__ row_start,
                const int* __restrict__ csr_src,
                const float* __restrict__ bias,
                void* __restrict__ out, int N) {
    int wave = threadIdx.x >> 6;
    int f = threadIdx.x & 63;
    int na = blockIdx.x * 8 + wave * 2;
    if (na >= N) return;
    int nb = na + 1;
    bool hasB = (nb < N);

    float2 va = unpack_f16x2(featb[(size_t)na * 64 + f]);
    float ax = va.x, ay = va.y;
    float bx = 0.f, by = 0.f;
    if (hasB) {
        float2 vb = unpack_f16x2(featb[(size_t)nb * 64 + f]);
        bx = vb.x;
        by = vb.y;
    }
    int ea = row_start[na], ea1 = row_start[na + 1];
    int eb = 0, eb1 = 0;
    if (hasB) { eb = ea1; eb1 = row_start[nb + 1]; }

    if (hasB && ea + 8 <= ea1 && eb + 8 <= eb1) {
        int sa[8], sb[8];
        #pragma unroll
        for (int j = 0; j < 8; j++) sa[j] = csr_src[ea + j];
        #pragma unroll
        for (int j = 0; j < 8; j++) sb[j] = csr_src[eb + j];
        ea += 8;
        eb += 8;
        while (ea + 8 <= ea1 && eb + 8 <= eb1) {
            unsigned wa[8], wb[8];
            #pragma unroll
            for (int j = 0; j < 8; j++) wa[j] = featb[(size_t)sa[j] * 64 + f];
            #pragma unroll
            for (int j = 0; j < 8; j++) wb[j] = featb[(size_t)sb[j] * 64 + f];
            int sna[8], snb[8];
            #pragma unroll
            for (int j = 0; j < 8; j++) sna[j] = csr_src[ea + j];
            #pragma unroll
            for (int j = 0; j < 8; j++) snb[j] = csr_src[eb + j];
            #pragma unroll
            for (int j = 0; j < 8; j++) {
                float2 u = unpack_f16x2(wa[j]);
                ax += u.x;
                ay += u.y;
            }
            #pragma unroll
            for (int j = 0; j < 8; j++) {
                float2 u = unpack_f16x2(wb[j]);
                bx += u.x;
                by += u.y;
            }
            #pragma unroll
            for (int j = 0; j < 8; j++) {
                sa[j] = sna[j];
                sb[j] = snb[j];
            }
            ea += 8;
            eb += 8;
        }
        unsigned wa[8], wb[8];
        #pragma unroll
        for (int j = 0; j < 8; j++) wa[j] = featb[(size_t)sa[j] * 64 + f];
        #pragma unroll
        for (int j = 0; j < 8; j++) wb[j] = featb[(size_t)sb[j] * 64 + f];
        #pragma unroll
        for (int j = 0; j < 8; j++) {
            float2 u = unpack_f16x2(wa[j]);
            ax += u.x;
            ay += u.y;
        }
        #pragma unroll
        for (int j = 0; j < 8; j++) {
            float2 u = unpack_f16x2(wb[j]);
            bx += u.x;
            by += u.y;
        }
        agg_full(featb, csr_src, ea, ea1, f, ax, ay);
        agg_full(featb, csr_src, eb, eb1, f, bx, by);
    } else {
        agg_full(featb, csr_src, ea, ea1, f, ax, ay);
        if (hasB) agg_full(featb, csr_src, eb, eb1, f, bx, by);
    }

    float dna = dinv[na];
    ax *= dna;
    ay *= dna;
    float2 bias2 = make_float2(0.f, 0.f);
    if (EPILOGUE) {
        bias2 = ((const float2*)bias)[f];
        ax = fmaxf(ax + bias2.x, 0.0f);
        ay = fmaxf(ay + bias2.y, 0.0f);
    }
    if (F16OUT) {
        ((unsigned*)out)[(size_t)na * 64 + f] = pack_f16x2(ax, ay);
    } else {
        float2 r;
        r.x = ax;
        r.y = ay;
        ((float2*)out)[(size_t)na * 64 + f] = r;
    }
    if (hasB) {
        float dnb = dinv[nb];
        bx *= dnb;
        by *= dnb;
        if (EPILOGUE) {
            bx = fmaxf(bx + bias2.x, 0.0f);
            by = fmaxf(by + bias2.y, 0.0f);
        }
        if (F16OUT) {
            ((unsigned*)out)[(size_t)nb * 64 + f] = pack_f16x2(bx, by);
        } else {
            float2 r;
            r.x = bx;
            r.y = by;
            ((float2*)out)[(size_t)nb * 64 + f] = r;
        }
    }
}

// ---------------- Fused MLP: t16 = dinv ⊙ (relu(A@W1+b1) @ W2) -------------
// Row-wise dependency only -> fuse both GEMMs per 64-row tile; H stays in LDS.
// MFMA f16 16x16x32, fp32 accum. LDS: 16+64+32 = 112KB -> 1 block/CU.
__global__ __launch_bounds__(256)
void mlp_kernel(const u16* __restrict__ A,     // [Mpad][128] f16
                const u16* __restrict__ W1t,   // [256][128] f16
                const u16* __restrict__ W2t,   // [128][256] f16
                const float* __restrict__ b1,
                const float* __restrict__ rscale,
                u16* __restrict__ C,           // [M][128] f16
                int M) {
    __shared__ __align__(16) u16 As[64 * 128];
    __shared__ __align__(16) u16 Wl[256 * 128];
    __shared__ __align__(16) u16 Hl[64 * 256];
    int tid = threadIdx.x;
    int w = tid >> 6;
    int l = tid & 63;
    int m0 = blockIdx.x * 64;
    int g = l >> 4;            // k-group 0..3
    int cl = l & 15;           // frag col/row lane index

    for (int q = tid; q < 1024; q += 256) {
        int r = q >> 4, c = q & 15;
        *(f16x8*)&As[r * 128 + ((c ^ (r & 15)) * 8)] =
            *(const f16x8*)(A + (size_t)(m0 + r) * 128 + c * 8);
    }
    for (int q = tid; q < 4096; q += 256) {
        int r = q >> 4, c = q & 15;
        *(f16x8*)&Wl[r * 128 + ((c ^ (r & 15)) * 8)] =
            *(const f16x8*)(W1t + (size_t)r * 128 + c * 8);
    }
    __syncthreads();

    // phase 1: H[64][256] = relu(A @ W1 + b1)
    {
        f32x4 acc[16];
        const f32x4 zero = {0.f, 0.f, 0.f, 0.f};
        #pragma unroll
        for (int nf = 0; nf < 16; nf++) acc[nf] = zero;
        int rowA = w * 16 + cl;
        #pragma unroll
        for (int kc = 0; kc < 4; kc++) {
            int ch = kc * 4 + g;
            f16x8 af = *(const f16x8*)&As[rowA * 128 + ((ch ^ (rowA & 15)) * 8)];
            #pragma unroll
            for (int nf = 0; nf < 16; nf++) {
                int rb = nf * 16 + cl;
                f16x8 bf = *(const f16x8*)&Wl[rb * 128 + ((ch ^ (rb & 15)) * 8)];
                acc[nf] = __builtin_amdgcn_mfma_f32_16x16x32_f16(af, bf, acc[nf], 0, 0, 0);
            }
        }
        int r0 = g * 4;
        #pragma unroll
        for (int nf = 0; nf < 16; nf++) {
            int col = nf * 16 + cl;
            float bb = b1[col];
            #pragma unroll
            for (int r = 0; r < 4; r++) {
                int lr = w * 16 + r0 + r;
                float v = fmaxf(acc[nf][r] + bb, 0.0f);
                int cc = col >> 3;
                Hl[lr * 256 + ((cc ^ (lr & 31)) * 8) + (col & 7)] = f16u(v);
            }
        }
    }
    __syncthreads();

    for (int q = tid; q < 4096; q += 256) {
        int r = q >> 5, c = q & 31;
        *(f16x8*)&Wl[r * 256 + ((c ^ (r & 31)) * 8)] =
            *(const f16x8*)(W2t + (size_t)r * 256 + c * 8);
    }
    __syncthreads();

    // phase 2: t = dinv ⊙ (H @ W2)
    {
        f32x4 acc[8];
        const f32x4 zero = {0.f, 0.f, 0.f, 0.f};
        #pragma unroll
        for (int nf = 0; nf < 8; nf++) acc[nf] = zero;
        int rowA = w * 16 + cl;
        #pragma unroll
        for (int kc = 0; kc < 8; kc++) {
            int ch = kc * 4 + g;
            f16x8 af = *(const f16x8*)&Hl[rowA * 256 + ((ch ^ (rowA & 31)) * 8)];
            #pragma unroll
            for (int nf = 0; nf < 8; nf++) {
                int rb = nf * 16 + cl;
                f16x8 bf = *(const f16x8*)&Wl[rb * 256 + ((ch ^ (rb & 31)) * 8)];
                acc[nf] = __builtin_amdgcn_mfma_f32_16x16x32_f16(af, bf, acc[nf], 0, 0, 0);
            }
        }
        int r0 = g * 4;
        #pragma unroll
        for (int r = 0; r < 4; r++) {
            int m = m0 + w * 16 + r0 + r;
            if (m >= M) continue;
            float rs = rscale[m];
            #pragma unroll
            for (int nf = 0; nf < 8; nf++) {
                int col = nf * 16 + cl;
                C[(size_t)m * 128 + col] = f16u(acc[nf][r] * rs);
            }
        }
    }
}

// ---------------- launch ----------------

static inline size_t align512(size_t x) { return (x + 511) & ~(size_t)511; }

extern "C" void kernel_launch(void* const* d_in, const int* in_sizes, int n_in,
                              void* d_out, int out_size, void* d_ws, size_t ws_size,
                              hipStream_t stream) {
    const float* x = (const float*)d_in[0];
    const int* ei = (const int*)d_in[1];
    const float* W1 = (const float*)d_in[2];
    const float* b1 = (const float*)d_in[3];
    const float* W2 = (const float*)d_in[4];
    const float* b2 = (const float*)d_in[5];
    float* out = (float*)d_out;

    const int N = in_sizes[0] / N_FEAT;      // 10000
    const int E = in_sizes[1] / 2;           // 640000
    const int* src = ei;
    const int* dst = ei + E;

    const int Mpad = ((N + 63) / 64) * 64;   // 10048 (MFMA staging pad)

    // workspace carve-up (~14 MB)
    char* ws = (char*)d_ws;
    size_t off = 0;
    float* dinv = (float*)(ws + off);    off += align512((size_t)N * 4);
    int* flag = (int*)(ws + off);        off += align512((size_t)64 * 4);
    int* row_start = (int*)(ws + off);   off += align512((size_t)(N + 1) * 4);
    int* csr_src = (int*)(ws + off);     off += align512((size_t)E * 4);
    unsigned* xs_b = (unsigned*)(ws + off);  off += align512((size_t)N * 64 * 4);
    u16* agg1h = (u16*)(ws + off);       off += align512((size_t)Mpad * N_FEAT * 2);
    u16* t16 = (u16*)(ws + off);         off += align512((size_t)N * OUT_CH * 2);
    u16* W1t = (u16*)(ws + off);         off += align512((size_t)HID * N_FEAT * 2);
    u16* W2t = (u16*)(ws + off);         off += align512((size_t)OUT_CH * HID * 2);
    u16* bh = (u16*)(ws + off);          off += align512((size_t)NB * N * 2);
    (void)ws_size;
    const int chunk = (E + NB - 1) / NB;

    // 1. CSR build: hist -> fused colscan+scan -> scat(+prescale+Wconv)
    hist_kernel<<<NB, 256, 0, stream>>>(dst, bh, flag, E, N, chunk);
    colscan_scan_kernel<<<NJ, 256, 0, stream>>>(bh, row_start, dinv, flag, N);
    scat_kernel<<<NB, 256, 0, stream>>>(src, dst, bh, row_start, csr_src,
                                        x, dinv, xs_b, W1, W2, W1t, W2t,
                                        E, N, chunk);

    // 2. agg1h = f16(A_norm @ x)
    agg_kernel<false, true><<<(N + 7) / 8, 256, 0, stream>>>(
        xs_b, dinv, row_start, csr_src, nullptr, agg1h, N);

    // 3. t16 = dinv ⊙ (relu(agg1h @ W1 + b1) @ W2)   [fused MFMA MLP]
    mlp_kernel<<<Mpad / 64, 256, 0, stream>>>(agg1h, W1t, W2t, b1, dinv, t16, N);

    // 4. out = relu(A_norm-aggregate of t16 + b2)
    agg_kernel<true, false><<<(N + 7) / 8, 256, 0, stream>>>(
        (const unsigned*)t16, dinv, row_start, csr_src, b2, out, N);
}